// Round 4
// baseline (273.479 us; speedup 1.0000x reference)
//
#include <hip/hip_runtime.h>

#define NH   12
#define ND   64
#define NSEQ 4096
#define NIT  16
#define MM   256   // rows per iteration chunk

// LDS pitches (bf16 elements). T_P*2 % 16 == 0 keeps ds_read_b128 aligned.
#define T_P  264   // XT/ET pitch
#define W_P  72    // WBT pitch

#define SM_XT   0
#define SM_ET   33792      // 64*264*2
#define SM_WBT  67584
#define SM_TOTAL 76800     // + 64*72*2

typedef __bf16 bf16_t;
typedef bf16_t bf16x8 __attribute__((ext_vector_type(8)));
typedef float  f32x4  __attribute__((ext_vector_type(4)));

__device__ __forceinline__ unsigned short f2bf(float f) {
    union { float f; unsigned u; } v; v.f = f;
    return (unsigned short)((v.u + 0x7FFFu + ((v.u >> 16) & 1u)) >> 16);
}

__device__ __forceinline__ bf16x8 pack8(float4 a, float4 b) {
    union { unsigned short u[8]; bf16x8 v; } r;
    r.u[0] = f2bf(a.x); r.u[1] = f2bf(a.y); r.u[2] = f2bf(a.z); r.u[3] = f2bf(a.w);
    r.u[4] = f2bf(b.x); r.u[5] = f2bf(b.y); r.u[6] = f2bf(b.z); r.u[7] = f2bf(b.w);
    return r.v;
}

// Barrier draining ONLY LDS ops; global loads/stores stay in flight across it.
__device__ __forceinline__ void barrier_lds() {
    asm volatile("s_waitcnt lgkmcnt(0)" ::: "memory");
    __builtin_amdgcn_s_barrier();
    asm volatile("" ::: "memory");
}

extern "C" __global__ void __launch_bounds__(1024, 4)
ttt_fused(const float* __restrict__ qg, const float* __restrict__ kg,
          const float* __restrict__ vg, const float* __restrict__ Wi,
          float* __restrict__ outg)
{
    extern __shared__ char smem[];
    unsigned short* XT  = (unsigned short*)(smem + SM_XT);   // x_tr transposed [d][m]
    unsigned short* ET  = (unsigned short*)(smem + SM_ET);   // err transposed [e][m]
    unsigned short* WBT = (unsigned short*)(smem + SM_WBT);  // W transposed bf16 [e][d]

    const int tid  = threadIdx.x;
    const int lane = tid & 63;
    const int wv   = tid >> 6;      // wave 0..15
    const int g    = lane >> 4;     // 0..3
    const int ln   = lane & 15;     // 0..15

    const int bh = blockIdx.x;
    const int b  = bh / NH;
    const int h  = bh - b * NH;

    const float* kb = kg + (size_t)bh * NSEQ * ND;
    const float* vb = vg + (size_t)bh * NSEQ * ND;
    const float* qb = qg + (size_t)bh * NSEQ * ND;
    float* ob = outg + (size_t)b * NSEQ * (NH * ND) + h * ND;

    const int r0 = wv << 4;          // wave's 16-row m-slice (A and C)
    const int d0 = (wv >> 2) << 4;   // wave's grad tile (B)
    const int e0 = (wv & 3) << 4;
    const float scale = 1.0f / 16384.0f;  // LR / (m*D)

    // staging mapping: thread owns rows (sR, sR+1) x cols sC..sC+7.
    // XT write bank = (4(sC+j) + (tid&127)) % 32 -> lane term spreads banks (2-way max, free).
    const int sR = (tid & 127) << 1;   // 0..254, even
    const int sC = (tid >> 7) << 3;    // 0..56

    // ---- prologue: issue chunk-0 globals (k staging, k frags, v frags)
    float4 ks[4], xq[4], vq[4], qr[4];
    {
        const float* kr = kb + (size_t)sR * ND + sC;
        ks[0] = *(const float4*)(kr);
        ks[1] = *(const float4*)(kr + 4);
        ks[2] = *(const float4*)(kr + ND);
        ks[3] = *(const float4*)(kr + ND + 4);
        const float* xr = kb + (size_t)(r0 + ln) * ND;
        xq[0] = *(const float4*)(xr + (g << 3));
        xq[1] = *(const float4*)(xr + (g << 3) + 4);
        xq[2] = *(const float4*)(xr + 32 + (g << 3));
        xq[3] = *(const float4*)(xr + 32 + (g << 3) + 4);
        const float* vp = vb + (size_t)(r0 + ln) * ND + (g << 2);
        vq[0] = *(const float4*)(vp);
        vq[1] = *(const float4*)(vp + 16);
        vq[2] = *(const float4*)(vp + 32);
        vq[3] = *(const float4*)(vp + 48);
    }

    // ---- W_init -> wf regs (wave-private f32 master) + WBT bf16
    float wf[4];
    {
        const float* wp = Wi + (size_t)h * ND * ND;
        ushort4 wq; unsigned short* wqp = (unsigned short*)&wq;
        #pragma unroll
        for (int j = 0; j < 4; ++j) {
            wf[j] = wp[(size_t)(d0 + (g << 2) + j) * ND + e0 + ln];
            wqp[j] = f2bf(wf[j]);
        }
        *(ushort4*)&WBT[(e0 + ln) * W_P + d0 + (g << 2)] = wq;
    }
    barrier_lds();   // WBT(W_0) visible

    for (int it = 0; it < NIT; ++it) {
        // ================= region 1: stage XT(it) | A(it) | C(it-1) =================
        // stage XT(it) from ks (frees 16 VGPR early)
        {
            #pragma unroll
            for (int j = 0; j < 8; ++j) {
                float flo = (j < 4) ? ((const float*)&ks[0])[j] : ((const float*)&ks[1])[j - 4];
                float fhi = (j < 4) ? ((const float*)&ks[2])[j] : ((const float*)&ks[3])[j - 4];
                unsigned pk = (unsigned)f2bf(flo) | ((unsigned)f2bf(fhi) << 16);
                *(unsigned*)&XT[(sC + j) * T_P + sR] = pk;
            }
        }

        // wfrag <- WBT (W_it); serves A (A-operand) and C (B-operand)
        bf16x8 wfrag[4][2];
        #pragma unroll
        for (int e = 0; e < 4; ++e)
            #pragma unroll
            for (int kx = 0; kx < 2; ++kx)
                wfrag[e][kx] = *(const bf16x8*)&WBT[((e << 4) + ln) * W_P + (kx << 5) + (g << 3)];

        // A(it): errT = W^T x_tr^T - y^T -> ET
        {
            bf16x8 xb0 = pack8(xq[0], xq[1]);
            bf16x8 xb1 = pack8(xq[2], xq[3]);
            #pragma unroll
            for (int e = 0; e < 4; ++e) {
                f32x4 acc = {0.f, 0.f, 0.f, 0.f};
                acc = __builtin_amdgcn_mfma_f32_16x16x32_bf16(wfrag[e][0], xb0, acc, 0, 0, 0);
                acc = __builtin_amdgcn_mfma_f32_16x16x32_bf16(wfrag[e][1], xb1, acc, 0, 0, 0);
                int rr = (e << 4) + (g << 2);
                ET[(rr + 0) * T_P + r0 + ln] = f2bf(acc[0] - vq[e].x);
                ET[(rr + 1) * T_P + r0 + ln] = f2bf(acc[1] - vq[e].y);
                ET[(rr + 2) * T_P + r0 + ln] = f2bf(acc[2] - vq[e].z);
                ET[(rr + 3) * T_P + r0 + ln] = f2bf(acc[3] - vq[e].w);
            }
        }

        // C(it-1): out = x_te * W_it  (same wfrag; fully off the recurrence path)
        if (it > 0) {
            bf16x8 a0 = pack8(qr[0], qr[1]);
            bf16x8 a1 = pack8(qr[2], qr[3]);
            #pragma unroll
            for (int e = 0; e < 4; ++e) {
                f32x4 oc = {0.f, 0.f, 0.f, 0.f};
                oc = __builtin_amdgcn_mfma_f32_16x16x32_bf16(a0, wfrag[e][0], oc, 0, 0, 0);
                oc = __builtin_amdgcn_mfma_f32_16x16x32_bf16(a1, wfrag[e][1], oc, 0, 0, 0);
                #pragma unroll
                for (int j = 0; j < 4; ++j)
                    __builtin_nontemporal_store(oc[j],
                        &ob[((size_t)((it - 1) * MM) + r0 + (g << 2) + j) * (NH * ND) + (e << 4) + ln]);
            }
        }

        // issue q(it) (consumed by C(it) next region-1 / epilogue)
        {
            const float* qrow = qb + ((size_t)(it * MM) + r0 + ln) * ND;
            qr[0] = *(const float4*)(qrow + (g << 3));
            qr[1] = *(const float4*)(qrow + (g << 3) + 4);
            qr[2] = *(const float4*)(qrow + 32 + (g << 3));
            qr[3] = *(const float4*)(qrow + 32 + (g << 3) + 4);
        }

        barrier_lds();   // alpha: XT(it), ET(it) visible

        // ================= region 2: B(it) + prefetch issues =================
        if (it + 1 < NIT) {
            const float* kr = kb + (size_t)((it + 1) * MM + sR) * ND + sC;
            ks[0] = *(const float4*)(kr);
            ks[1] = *(const float4*)(kr + 4);
            ks[2] = *(const float4*)(kr + ND);
            ks[3] = *(const float4*)(kr + ND + 4);
            const float* xr = kb + (size_t)((it + 1) * MM + r0 + ln) * ND;
            xq[0] = *(const float4*)(xr + (g << 3));
            xq[1] = *(const float4*)(xr + (g << 3) + 4);
            xq[2] = *(const float4*)(xr + 32 + (g << 3));
            xq[3] = *(const float4*)(xr + 32 + (g << 3) + 4);
            const float* vp = vb + (size_t)((it + 1) * MM + r0 + ln) * ND + (g << 2);
            vq[0] = *(const float4*)(vp);
            vq[1] = *(const float4*)(vp + 16);
            vq[2] = *(const float4*)(vp + 32);
            vq[3] = *(const float4*)(vp + 48);
        }

        // B(it): grad = x_tr^T err ; W -= grad/16384 ; WBT <- W_{it+1}
        {
            f32x4 ga = {0.f, 0.f, 0.f, 0.f};
            #pragma unroll
            for (int kx = 0; kx < 8; ++kx) {
                bf16x8 af  = *(const bf16x8*)&XT[(d0 + ln) * T_P + (kx << 5) + (g << 3)];
                bf16x8 bf_ = *(const bf16x8*)&ET[(e0 + ln) * T_P + (kx << 5) + (g << 3)];
                ga = __builtin_amdgcn_mfma_f32_16x16x32_bf16(af, bf_, ga, 0, 0, 0);
            }
            ushort4 wq; unsigned short* wqp = (unsigned short*)&wq;
            #pragma unroll
            for (int j = 0; j < 4; ++j) {
                wf[j] -= scale * ga[j];
                wqp[j] = f2bf(wf[j]);
            }
            *(ushort4*)&WBT[(e0 + ln) * W_P + d0 + (g << 2)] = wq;
        }

        barrier_lds();   // beta: WBT(W_{it+1}) visible
    }

    // ================= epilogue: C(NIT-1) with W_NIT =================
    {
        bf16x8 a0 = pack8(qr[0], qr[1]);
        bf16x8 a1 = pack8(qr[2], qr[3]);
        #pragma unroll
        for (int e = 0; e < 4; ++e) {
            bf16x8 w0 = *(const bf16x8*)&WBT[((e << 4) + ln) * W_P + (g << 3)];
            bf16x8 w1 = *(const bf16x8*)&WBT[((e << 4) + ln) * W_P + 32 + (g << 3)];
            f32x4 oc = {0.f, 0.f, 0.f, 0.f};
            oc = __builtin_amdgcn_mfma_f32_16x16x32_bf16(a0, w0, oc, 0, 0, 0);
            oc = __builtin_amdgcn_mfma_f32_16x16x32_bf16(a1, w1, oc, 0, 0, 0);
            #pragma unroll
            for (int j = 0; j < 4; ++j)
                __builtin_nontemporal_store(oc[j],
                    &ob[((size_t)((NIT - 1) * MM) + r0 + (g << 2) + j) * (NH * ND) + (e << 4) + ln]);
        }
    }
}

extern "C" void kernel_launch(void* const* d_in, const int* in_sizes, int n_in,
                              void* d_out, int out_size, void* d_ws, size_t ws_size,
                              hipStream_t stream) {
    const float* q  = (const float*)d_in[0];
    const float* k  = (const float*)d_in[1];
    const float* v  = (const float*)d_in[2];
    const float* Wi = (const float*)d_in[3];
    float* out = (float*)d_out;

    int grid = in_sizes[0] / (NSEQ * ND);   // B * H = 192
    hipFuncSetAttribute((const void*)ttt_fused,
                        hipFuncAttributeMaxDynamicSharedMemorySize, SM_TOTAL);
    hipLaunchKernelGGL(ttt_fused, dim3(grid), dim3(1024), SM_TOTAL, stream,
                       q, k, v, Wi, out);
}

// Round 5
// 270.019 us; speedup vs baseline: 1.0128x; 1.0128x over previous
//
#include <hip/hip_runtime.h>

#define NH   12
#define ND   64
#define NSEQ 4096
#define NIT  16
#define MM   256   // rows per iteration chunk

// LDS pitches (bf16 elements). T_P*2 % 16 == 0 keeps ds_read_b128 aligned.
#define T_P  264   // XT/ET pitch
#define W_P  72    // WBT pitch

#define SM_XT   0
#define SM_ET   33792      // 64*264*2
#define SM_WBT  67584
#define SM_TOTAL 76800     // + 64*72*2

typedef __bf16 bf16_t;
typedef bf16_t bf16x8 __attribute__((ext_vector_type(8)));
typedef float  f32x4  __attribute__((ext_vector_type(4)));

__device__ __forceinline__ unsigned short f2bf(float f) {
    union { float f; unsigned u; } v; v.f = f;
    return (unsigned short)((v.u + 0x7FFFu + ((v.u >> 16) & 1u)) >> 16);
}

__device__ __forceinline__ bf16x8 pack8(float4 a, float4 b) {
    union { unsigned short u[8]; bf16x8 v; } r;
    r.u[0] = f2bf(a.x); r.u[1] = f2bf(a.y); r.u[2] = f2bf(a.z); r.u[3] = f2bf(a.w);
    r.u[4] = f2bf(b.x); r.u[5] = f2bf(b.y); r.u[6] = f2bf(b.z); r.u[7] = f2bf(b.w);
    return r.v;
}

// Barrier draining ONLY LDS ops; global loads/stores stay in flight across it.
__device__ __forceinline__ void barrier_lds() {
    asm volatile("s_waitcnt lgkmcnt(0)" ::: "memory");
    __builtin_amdgcn_s_barrier();
    asm volatile("" ::: "memory");
}

extern "C" __global__ void __launch_bounds__(1024)
__attribute__((amdgpu_waves_per_eu(4, 4)))   // force allocator to 4 waves/EU -> 128 VGPR budget
ttt_fused(const float* __restrict__ qg, const float* __restrict__ kg,
          const float* __restrict__ vg, const float* __restrict__ Wi,
          float* __restrict__ outg)
{
    extern __shared__ char smem[];
    unsigned short* XT  = (unsigned short*)(smem + SM_XT);   // x_tr transposed [d][m]
    unsigned short* ET  = (unsigned short*)(smem + SM_ET);   // err transposed [e][m]
    unsigned short* WBT = (unsigned short*)(smem + SM_WBT);  // W transposed bf16 [e][d]

    const int tid  = threadIdx.x;
    const int lane = tid & 63;
    const int wv   = tid >> 6;      // wave 0..15
    const int g    = lane >> 4;     // 0..3
    const int ln   = lane & 15;     // 0..15

    const int bh = blockIdx.x;
    const int b  = bh / NH;
    const int h  = bh - b * NH;

    const float* kb = kg + (size_t)bh * NSEQ * ND;
    const float* vb = vg + (size_t)bh * NSEQ * ND;
    const float* qb = qg + (size_t)bh * NSEQ * ND;
    float* ob = outg + (size_t)b * NSEQ * (NH * ND) + h * ND;

    const int r0 = wv << 4;          // wave's 16-row m-slice (A and C)
    const int d0 = (wv >> 2) << 4;   // wave's grad tile (B)
    const int e0 = (wv & 3) << 4;
    const float scale = 1.0f / 16384.0f;  // LR / (m*D)

    // staging mapping: thread owns rows (sR, sR+1) x cols sC..sC+7.
    // XT write bank = (4(sC+j) + (tid&127)) % 32 -> lane term spreads banks (2-way max, free).
    const int sR = (tid & 127) << 1;   // 0..254, even
    const int sC = (tid >> 7) << 3;    // 0..56

    // ---- prologue: issue chunk-0 globals (k staging, k frags, v frags)
    float4 ks[4], xq[4], vq[4], qr[4];
    {
        const float* kr = kb + (size_t)sR * ND + sC;
        ks[0] = *(const float4*)(kr);
        ks[1] = *(const float4*)(kr + 4);
        ks[2] = *(const float4*)(kr + ND);
        ks[3] = *(const float4*)(kr + ND + 4);
        const float* xr = kb + (size_t)(r0 + ln) * ND;
        xq[0] = *(const float4*)(xr + (g << 3));
        xq[1] = *(const float4*)(xr + (g << 3) + 4);
        xq[2] = *(const float4*)(xr + 32 + (g << 3));
        xq[3] = *(const float4*)(xr + 32 + (g << 3) + 4);
        const float* vp = vb + (size_t)(r0 + ln) * ND + (g << 2);
        vq[0] = *(const float4*)(vp);
        vq[1] = *(const float4*)(vp + 16);
        vq[2] = *(const float4*)(vp + 32);
        vq[3] = *(const float4*)(vp + 48);
    }

    // ---- W_init -> wf regs (wave-private f32 master) + WBT bf16
    float wf[4];
    {
        const float* wp = Wi + (size_t)h * ND * ND;
        ushort4 wq; unsigned short* wqp = (unsigned short*)&wq;
        #pragma unroll
        for (int j = 0; j < 4; ++j) {
            wf[j] = wp[(size_t)(d0 + (g << 2) + j) * ND + e0 + ln];
            wqp[j] = f2bf(wf[j]);
        }
        *(ushort4*)&WBT[(e0 + ln) * W_P + d0 + (g << 2)] = wq;
    }
    barrier_lds();   // WBT(W_0) visible

    for (int it = 0; it < NIT; ++it) {
        // ================= region 1: stage XT(it) | A(it) | C(it-1) =================
        // stage XT(it) from ks (frees 16 VGPR early)
        {
            #pragma unroll
            for (int j = 0; j < 8; ++j) {
                float flo = (j < 4) ? ((const float*)&ks[0])[j] : ((const float*)&ks[1])[j - 4];
                float fhi = (j < 4) ? ((const float*)&ks[2])[j] : ((const float*)&ks[3])[j - 4];
                unsigned pk = (unsigned)f2bf(flo) | ((unsigned)f2bf(fhi) << 16);
                *(unsigned*)&XT[(sC + j) * T_P + sR] = pk;
            }
        }

        // wfrag <- WBT (W_it); serves A (A-operand) and C (B-operand)
        bf16x8 wfrag[4][2];
        #pragma unroll
        for (int e = 0; e < 4; ++e)
            #pragma unroll
            for (int kx = 0; kx < 2; ++kx)
                wfrag[e][kx] = *(const bf16x8*)&WBT[((e << 4) + ln) * W_P + (kx << 5) + (g << 3)];

        // A(it): errT = W^T x_tr^T - y^T -> ET
        {
            bf16x8 xb0 = pack8(xq[0], xq[1]);
            bf16x8 xb1 = pack8(xq[2], xq[3]);
            #pragma unroll
            for (int e = 0; e < 4; ++e) {
                f32x4 acc = {0.f, 0.f, 0.f, 0.f};
                acc = __builtin_amdgcn_mfma_f32_16x16x32_bf16(wfrag[e][0], xb0, acc, 0, 0, 0);
                acc = __builtin_amdgcn_mfma_f32_16x16x32_bf16(wfrag[e][1], xb1, acc, 0, 0, 0);
                int rr = (e << 4) + (g << 2);
                ET[(rr + 0) * T_P + r0 + ln] = f2bf(acc[0] - vq[e].x);
                ET[(rr + 1) * T_P + r0 + ln] = f2bf(acc[1] - vq[e].y);
                ET[(rr + 2) * T_P + r0 + ln] = f2bf(acc[2] - vq[e].z);
                ET[(rr + 3) * T_P + r0 + ln] = f2bf(acc[3] - vq[e].w);
            }
        }

        // C(it-1): out = x_te * W_it  (same wfrag; fully off the recurrence path)
        if (it > 0) {
            bf16x8 a0 = pack8(qr[0], qr[1]);
            bf16x8 a1 = pack8(qr[2], qr[3]);
            #pragma unroll
            for (int e = 0; e < 4; ++e) {
                f32x4 oc = {0.f, 0.f, 0.f, 0.f};
                oc = __builtin_amdgcn_mfma_f32_16x16x32_bf16(a0, wfrag[e][0], oc, 0, 0, 0);
                oc = __builtin_amdgcn_mfma_f32_16x16x32_bf16(a1, wfrag[e][1], oc, 0, 0, 0);
                #pragma unroll
                for (int j = 0; j < 4; ++j)
                    ob[((size_t)((it - 1) * MM) + r0 + (g << 2) + j) * (NH * ND) + (e << 4) + ln] = oc[j];
            }
        }

        // issue q(it) (consumed by C(it) next region-1 / epilogue)
        {
            const float* qrow = qb + ((size_t)(it * MM) + r0 + ln) * ND;
            qr[0] = *(const float4*)(qrow + (g << 3));
            qr[1] = *(const float4*)(qrow + (g << 3) + 4);
            qr[2] = *(const float4*)(qrow + 32 + (g << 3));
            qr[3] = *(const float4*)(qrow + 32 + (g << 3) + 4);
        }

        barrier_lds();   // alpha: XT(it), ET(it) visible

        // ================= region 2: B(it) + prefetch issues =================
        if (it + 1 < NIT) {
            const float* kr = kb + (size_t)((it + 1) * MM + sR) * ND + sC;
            ks[0] = *(const float4*)(kr);
            ks[1] = *(const float4*)(kr + 4);
            ks[2] = *(const float4*)(kr + ND);
            ks[3] = *(const float4*)(kr + ND + 4);
            const float* xr = kb + (size_t)((it + 1) * MM + r0 + ln) * ND;
            xq[0] = *(const float4*)(xr + (g << 3));
            xq[1] = *(const float4*)(xr + (g << 3) + 4);
            xq[2] = *(const float4*)(xr + 32 + (g << 3));
            xq[3] = *(const float4*)(xr + 32 + (g << 3) + 4);
            const float* vp = vb + (size_t)((it + 1) * MM + r0 + ln) * ND + (g << 2);
            vq[0] = *(const float4*)(vp);
            vq[1] = *(const float4*)(vp + 16);
            vq[2] = *(const float4*)(vp + 32);
            vq[3] = *(const float4*)(vp + 48);
        }

        // B(it): grad = x_tr^T err ; W -= grad/16384 ; WBT <- W_{it+1}
        {
            f32x4 ga = {0.f, 0.f, 0.f, 0.f};
            #pragma unroll
            for (int kx = 0; kx < 8; ++kx) {
                bf16x8 af  = *(const bf16x8*)&XT[(d0 + ln) * T_P + (kx << 5) + (g << 3)];
                bf16x8 bf_ = *(const bf16x8*)&ET[(e0 + ln) * T_P + (kx << 5) + (g << 3)];
                ga = __builtin_amdgcn_mfma_f32_16x16x32_bf16(af, bf_, ga, 0, 0, 0);
            }
            ushort4 wq; unsigned short* wqp = (unsigned short*)&wq;
            #pragma unroll
            for (int j = 0; j < 4; ++j) {
                wf[j] -= scale * ga[j];
                wqp[j] = f2bf(wf[j]);
            }
            *(ushort4*)&WBT[(e0 + ln) * W_P + d0 + (g << 2)] = wq;
        }

        barrier_lds();   // beta: WBT(W_{it+1}) visible
    }

    // ================= epilogue: C(NIT-1) with W_NIT =================
    {
        bf16x8 a0 = pack8(qr[0], qr[1]);
        bf16x8 a1 = pack8(qr[2], qr[3]);
        #pragma unroll
        for (int e = 0; e < 4; ++e) {
            bf16x8 w0 = *(const bf16x8*)&WBT[((e << 4) + ln) * W_P + (g << 3)];
            bf16x8 w1 = *(const bf16x8*)&WBT[((e << 4) + ln) * W_P + 32 + (g << 3)];
            f32x4 oc = {0.f, 0.f, 0.f, 0.f};
            oc = __builtin_amdgcn_mfma_f32_16x16x32_bf16(a0, w0, oc, 0, 0, 0);
            oc = __builtin_amdgcn_mfma_f32_16x16x32_bf16(a1, w1, oc, 0, 0, 0);
            #pragma unroll
            for (int j = 0; j < 4; ++j)
                ob[((size_t)((NIT - 1) * MM) + r0 + (g << 2) + j) * (NH * ND) + (e << 4) + ln] = oc[j];
        }
    }
}

extern "C" void kernel_launch(void* const* d_in, const int* in_sizes, int n_in,
                              void* d_out, int out_size, void* d_ws, size_t ws_size,
                              hipStream_t stream) {
    const float* q  = (const float*)d_in[0];
    const float* k  = (const float*)d_in[1];
    const float* v  = (const float*)d_in[2];
    const float* Wi = (const float*)d_in[3];
    float* out = (float*)d_out;

    int grid = in_sizes[0] / (NSEQ * ND);   // B * H = 192
    hipFuncSetAttribute((const void*)ttt_fused,
                        hipFuncAttributeMaxDynamicSharedMemorySize, SM_TOTAL);
    hipLaunchKernelGGL(ttt_fused, dim3(grid), dim3(1024), SM_TOTAL, stream,
                       q, k, v, Wi, out);
}

// Round 6
// 176.553 us; speedup vs baseline: 1.5490x; 1.5294x over previous
//
#include <hip/hip_runtime.h>

#define NH   12
#define ND   64
#define NSEQ 4096
#define NIT  16
#define MM   256   // rows per iteration chunk

// LDS pitches (bf16 elements)
#define X_P  72    // X row-major pitch (256 x 72)
#define T_P  264   // XT/ET pitch (64 x 264)
#define W_P  72    // WBT pitch (64 x 72)

// static LDS layout (bytes) — 147456 <= 163840 so only ONE block/CU fits:
// compiler then targets 4 waves/EU -> 128-VGPR budget (kills the R3-R5 spill).
#define SM_X    0
#define SM_XT0  36864
#define SM_XT1  70656
#define SM_ET   104448
#define SM_WBT  138240
#define SM_TOTAL 147456

typedef __bf16 bf16_t;
typedef bf16_t bf16x8 __attribute__((ext_vector_type(8)));
typedef float  f32x4  __attribute__((ext_vector_type(4)));
typedef unsigned short u16x8 __attribute__((ext_vector_type(8)));

static __device__ __forceinline__ unsigned short f2bf(float f) {
    union { float f; unsigned u; } v; v.f = f;
    return (unsigned short)((v.u + 0x7FFFu + ((v.u >> 16) & 1u)) >> 16);
}

static __device__ __forceinline__ bf16x8 pack8(float4 a, float4 b) {
    union { unsigned short u[8]; bf16x8 v; } r;
    r.u[0] = f2bf(a.x); r.u[1] = f2bf(a.y); r.u[2] = f2bf(a.z); r.u[3] = f2bf(a.w);
    r.u[4] = f2bf(b.x); r.u[5] = f2bf(b.y); r.u[6] = f2bf(b.z); r.u[7] = f2bf(b.w);
    return r.v;
}

// Barrier draining ONLY LDS ops; global loads/stores stay in flight across it.
static __device__ __forceinline__ void barrier_lds() {
    asm volatile("s_waitcnt lgkmcnt(0)" ::: "memory");
    __builtin_amdgcn_s_barrier();
    asm volatile("" ::: "memory");
}

extern "C" __global__ void __launch_bounds__(1024)
ttt_fused(const float* __restrict__ qg, const float* __restrict__ kg,
          const float* __restrict__ vg, const float* __restrict__ Wi,
          float* __restrict__ outg)
{
    __shared__ char smem[SM_TOTAL] __attribute__((aligned(16)));
    unsigned short* X   = (unsigned short*)(smem + SM_X);    // x_tr row-major [m][d]
    unsigned short* ET  = (unsigned short*)(smem + SM_ET);   // err transposed [e][m]
    unsigned short* WBT = (unsigned short*)(smem + SM_WBT);  // W transposed bf16 [e][d]

    const int tid  = threadIdx.x;
    const int lane = tid & 63;
    const int wv   = tid >> 6;      // wave 0..15
    const int g    = lane >> 4;     // 0..3
    const int ln   = lane & 15;     // 0..15

    const int bh = blockIdx.x;
    const int b  = bh / NH;
    const int h  = bh - b * NH;

    const float* kb = kg + (size_t)bh * NSEQ * ND;
    const float* vb = vg + (size_t)bh * NSEQ * ND;
    const float* qb = qg + (size_t)bh * NSEQ * ND;
    float* ob = outg + (size_t)b * NSEQ * (NH * ND) + h * ND;

    const int r0 = wv << 4;          // wave's 16-row m-slice (A and C)
    const int d0 = (wv >> 2) << 4;   // wave's grad tile (B)
    const int e0 = (wv & 3) << 4;
    const float scale = 1.0f / 16384.0f;  // LR / (m*D)

    // staging ownership: thread -> rows (sR, sR+1) x cols sC..sC+7
    const int sR = (tid & 127) << 1;   // 0..254, even
    const int sC = (tid >> 7) << 3;    // 0..56

    // ---- prologue: issue chunk-0 globals
    float4 ks[4], vq[4], qr[4];
    {
        const float* kr = kb + (size_t)sR * ND + sC;
        ks[0] = *(const float4*)(kr);
        ks[1] = *(const float4*)(kr + 4);
        ks[2] = *(const float4*)(kr + ND);
        ks[3] = *(const float4*)(kr + ND + 4);
        const float* vp = vb + (size_t)(r0 + ln) * ND + (g << 2);
        vq[0] = *(const float4*)(vp);
        vq[1] = *(const float4*)(vp + 16);
        vq[2] = *(const float4*)(vp + 32);
        vq[3] = *(const float4*)(vp + 48);
    }

    // ---- W_init -> wf regs (wave-private f32 master) + WBT bf16
    float wf[4];
    {
        const float* wp = Wi + (size_t)h * ND * ND;
        ushort4 wq; unsigned short* wqp = (unsigned short*)&wq;
        #pragma unroll
        for (int j = 0; j < 4; ++j) {
            wf[j] = wp[(size_t)(d0 + (g << 2) + j) * ND + e0 + ln];
            wqp[j] = f2bf(wf[j]);
        }
        *(ushort4*)&WBT[(e0 + ln) * W_P + d0 + (g << 2)] = wq;
    }

    // ---- stage chunk 0 -> X (row-major) + XT0 (transposed)
    {
        unsigned short* XTn = (unsigned short*)(smem + SM_XT0);
        union { unsigned short u[8]; u16x8 v; } lo, hi;
        #pragma unroll
        for (int j = 0; j < 8; ++j) {
            lo.u[j] = f2bf(j < 4 ? ((const float*)&ks[0])[j] : ((const float*)&ks[1])[j - 4]);
            hi.u[j] = f2bf(j < 4 ? ((const float*)&ks[2])[j] : ((const float*)&ks[3])[j - 4]);
        }
        *(u16x8*)&X[(size_t)sR * X_P + sC]       = lo.v;
        *(u16x8*)&X[(size_t)(sR + 1) * X_P + sC] = hi.v;
        #pragma unroll
        for (int j = 0; j < 8; ++j)
            *(unsigned*)&XTn[(sC + j) * T_P + sR] = (unsigned)lo.u[j] | ((unsigned)hi.u[j] << 16);
    }
    barrier_lds();   // X/XT0 (x_tr(0)), WBT (W_0) visible

    int cur = 0;
    for (int it = 0; it < NIT; ++it) {
        unsigned short* XTc = (unsigned short*)(smem + (cur ? SM_XT1 : SM_XT0));
        unsigned short* XTn = (unsigned short*)(smem + (cur ? SM_XT0 : SM_XT1));

        // ================= region 1: A(it) | C(it-1) =================
        bf16x8 aq0, aq1;
        if (it > 0) { aq0 = pack8(qr[0], qr[1]); aq1 = pack8(qr[2], qr[3]); }

        // A(it): errT = W^T x_tr^T - y^T -> ET (wfrag transient per-e)
        {
            bf16x8 xb0 = *(const bf16x8*)&X[(r0 + ln) * X_P + (g << 3)];
            bf16x8 xb1 = *(const bf16x8*)&X[(r0 + ln) * X_P + 32 + (g << 3)];
            #pragma unroll
            for (int e = 0; e < 4; ++e) {
                bf16x8 w0 = *(const bf16x8*)&WBT[((e << 4) + ln) * W_P + (g << 3)];
                bf16x8 w1 = *(const bf16x8*)&WBT[((e << 4) + ln) * W_P + 32 + (g << 3)];
                f32x4 acc = {0.f, 0.f, 0.f, 0.f};
                acc = __builtin_amdgcn_mfma_f32_16x16x32_bf16(w0, xb0, acc, 0, 0, 0);
                acc = __builtin_amdgcn_mfma_f32_16x16x32_bf16(w1, xb1, acc, 0, 0, 0);
                int rr = (e << 4) + (g << 2);
                ET[(rr + 0) * T_P + r0 + ln] = f2bf(acc[0] - vq[e].x);
                ET[(rr + 1) * T_P + r0 + ln] = f2bf(acc[1] - vq[e].y);
                ET[(rr + 2) * T_P + r0 + ln] = f2bf(acc[2] - vq[e].z);
                ET[(rr + 3) * T_P + r0 + ln] = f2bf(acc[3] - vq[e].w);
            }
        }

        // C(it-1): out = x_te * W_it (re-reads WBT; off the recurrence path)
        if (it > 0) {
            #pragma unroll
            for (int e = 0; e < 4; ++e) {
                bf16x8 w0 = *(const bf16x8*)&WBT[((e << 4) + ln) * W_P + (g << 3)];
                bf16x8 w1 = *(const bf16x8*)&WBT[((e << 4) + ln) * W_P + 32 + (g << 3)];
                f32x4 oc = {0.f, 0.f, 0.f, 0.f};
                oc = __builtin_amdgcn_mfma_f32_16x16x32_bf16(aq0, w0, oc, 0, 0, 0);
                oc = __builtin_amdgcn_mfma_f32_16x16x32_bf16(aq1, w1, oc, 0, 0, 0);
                #pragma unroll
                for (int j = 0; j < 4; ++j)
                    ob[((size_t)((it - 1) * MM) + r0 + (g << 2) + j) * (NH * ND) + (e << 4) + ln] = oc[j];
            }
        }

        barrier_lds();   // alpha: ET(it) visible; A's X reads drained

        // ================= region 2: B(it) | stage(it+1) | prefetch issues =================
        if (it + 1 < NIT) {
            const float* kr = kb + (size_t)((it + 1) * MM + sR) * ND + sC;
            ks[0] = *(const float4*)(kr);
            ks[1] = *(const float4*)(kr + 4);
            ks[2] = *(const float4*)(kr + ND);
            ks[3] = *(const float4*)(kr + ND + 4);
        }

        // B(it): grad = x_tr^T err ; W -= grad/16384 ; WBT <- W_{it+1}
        {
            f32x4 ga = {0.f, 0.f, 0.f, 0.f};
            #pragma unroll
            for (int kx = 0; kx < 8; ++kx) {
                bf16x8 af  = *(const bf16x8*)&XTc[(d0 + ln) * T_P + (kx << 5) + (g << 3)];
                bf16x8 bf_ = *(const bf16x8*)&ET[(e0 + ln) * T_P + (kx << 5) + (g << 3)];
                ga = __builtin_amdgcn_mfma_f32_16x16x32_bf16(af, bf_, ga, 0, 0, 0);
            }
            ushort4 wq; unsigned short* wqp = (unsigned short*)&wq;
            #pragma unroll
            for (int j = 0; j < 4; ++j) {
                wf[j] -= scale * ga[j];
                wqp[j] = f2bf(wf[j]);
            }
            *(ushort4*)&WBT[(e0 + ln) * W_P + d0 + (g << 2)] = wq;
        }

        // stage x_tr(it+1) -> X + XT[next] (ks consumed inside region; never crosses a barrier)
        if (it + 1 < NIT) {
            union { unsigned short u[8]; u16x8 v; } lo, hi;
            #pragma unroll
            for (int j = 0; j < 8; ++j) {
                lo.u[j] = f2bf(j < 4 ? ((const float*)&ks[0])[j] : ((const float*)&ks[1])[j - 4]);
                hi.u[j] = f2bf(j < 4 ? ((const float*)&ks[2])[j] : ((const float*)&ks[3])[j - 4]);
            }
            *(u16x8*)&X[(size_t)sR * X_P + sC]       = lo.v;
            *(u16x8*)&X[(size_t)(sR + 1) * X_P + sC] = hi.v;
            #pragma unroll
            for (int j = 0; j < 8; ++j)
                *(unsigned*)&XTn[(sC + j) * T_P + sR] = (unsigned)lo.u[j] | ((unsigned)hi.u[j] << 16);

            // v(it+1): consumed mid next region-1 (in flight across beta only)
            const float* vp = vb + (size_t)((it + 1) * MM + r0 + ln) * ND + (g << 2);
            vq[0] = *(const float4*)(vp);
            vq[1] = *(const float4*)(vp + 16);
            vq[2] = *(const float4*)(vp + 32);
            vq[3] = *(const float4*)(vp + 48);
        }

        // q(it): consumed by C(it) at start of next region-1 / epilogue
        {
            const float* qrow = qb + ((size_t)(it * MM) + r0 + ln) * ND;
            qr[0] = *(const float4*)(qrow + (g << 3));
            qr[1] = *(const float4*)(qrow + (g << 3) + 4);
            qr[2] = *(const float4*)(qrow + 32 + (g << 3));
            qr[3] = *(const float4*)(qrow + 32 + (g << 3) + 4);
        }

        barrier_lds();   // beta: WBT(W_{it+1}), X/XT[next] (x_tr(it+1)) visible
        cur ^= 1;
    }

    // ================= epilogue: C(NIT-1) with W_NIT =================
    {
        bf16x8 a0 = pack8(qr[0], qr[1]);
        bf16x8 a1 = pack8(qr[2], qr[3]);
        #pragma unroll
        for (int e = 0; e < 4; ++e) {
            bf16x8 w0 = *(const bf16x8*)&WBT[((e << 4) + ln) * W_P + (g << 3)];
            bf16x8 w1 = *(const bf16x8*)&WBT[((e << 4) + ln) * W_P + 32 + (g << 3)];
            f32x4 oc = {0.f, 0.f, 0.f, 0.f};
            oc = __builtin_amdgcn_mfma_f32_16x16x32_bf16(a0, w0, oc, 0, 0, 0);
            oc = __builtin_amdgcn_mfma_f32_16x16x32_bf16(a1, w1, oc, 0, 0, 0);
            #pragma unroll
            for (int j = 0; j < 4; ++j)
                ob[((size_t)((NIT - 1) * MM) + r0 + (g << 2) + j) * (NH * ND) + (e << 4) + ln] = oc[j];
        }
    }
}

extern "C" void kernel_launch(void* const* d_in, const int* in_sizes, int n_in,
                              void* d_out, int out_size, void* d_ws, size_t ws_size,
                              hipStream_t stream) {
    const float* q  = (const float*)d_in[0];
    const float* k  = (const float*)d_in[1];
    const float* v  = (const float*)d_in[2];
    const float* Wi = (const float*)d_in[3];
    float* out = (float*)d_out;

    int grid = in_sizes[0] / (NSEQ * ND);   // B * H = 192
    hipLaunchKernelGGL(ttt_fused, dim3(grid), dim3(1024), 0, stream,
                       q, k, v, Wi, out);
}